// Round 1
// baseline (482.051 us; speedup 1.0000x reference)
//
#include <hip/hip_runtime.h>

#define IMGS 96
#define HW   262144      // 512*512
#define NPTS 12288       // 96*128
#define OOBV 1e-5f

// ws layout (float offsets)
static constexpr size_t PYR_OFF   = 0;        // 8,388,576 floats (levels 1..9)
static constexpr size_t P_OFF     = 8388576;  // 24576
static constexpr size_t SQ_OFF    = 8413152;  // 24576
static constexpr size_t PLMAX_OFF = 8437728;  // 11 floats (plmax[0..10])
static constexpr size_t CNT_OFF   = 8437739;  // 1 int
static constexpr size_t LIST_OFF  = 8437740;  // 12288 ints
// total ~33.8 MB

__device__ __forceinline__ int clampi(int v, int lo, int hi) {
    v = v < lo ? lo : v;
    return v > hi ? hi : v;
}

// ---- masks_out scatter + dedup'd owner list of set pixels ----
__global__ void k_scatter(const float* __restrict__ pts, float* __restrict__ mo,
                          int* __restrict__ cnt, int* __restrict__ plist) {
    int i = blockIdx.x * blockDim.x + threadIdx.x;
    if (i >= NPTS) return;
    float px = pts[2*i], py = pts[2*i+1];
    int xi = clampi((int)rintf(px), 0, 511);
    int yi = clampi((int)rintf(py), 0, 511);
    int gp = (i >> 7) * HW + yi * 512 + xi;
    float old = atomicExch(&mo[gp], 1.0f);
    if (old == 0.0f) {                 // first claimer owns this pixel
        int k = atomicAdd(cnt, 1);
        plist[k] = gp;
    }
}

// ---- level 1 (256^2) from -masks_target only (0.01*mo added as correction) ----
__global__ void k_lvl1(const float* __restrict__ mt, float* __restrict__ out) {
    int t = blockIdx.x * blockDim.x + threadIdx.x;
    if (t >= IMGS * 65536) return;
    int j = t & 255, i = (t >> 8) & 255, img = t >> 16;
    const float* m = mt + (size_t)img * HW;
    float s = 0.0f;
    #pragma unroll
    for (int dy = -1; dy <= 1; ++dy) {
        int y = 2*i + dy;
        #pragma unroll
        for (int dx = -1; dx <= 1; ++dx) {
            int x = 2*j + dx;
            s += (y >= 0 && y < 512 && x >= 0 && x < 512) ? -m[y*512 + x] : OOBV;
        }
    }
    out[t] = s / 9.0f;
}

// ---- sparse correction: each set pixel adds 0.01/9 to covering lvl1 cells ----
__global__ void k_corr1(const int* __restrict__ cnt, const int* __restrict__ plist,
                        float* __restrict__ lvl1) {
    int k = blockIdx.x * blockDim.x + threadIdx.x;
    if (k >= *cnt) return;
    int gp = plist[k];
    int img = gp >> 18;
    int r = gp & (HW - 1);
    int y = r >> 9, x = r & 511;
    float* L = lvl1 + (size_t)img * 65536;
    const float c = 0.01f / 9.0f;
    int ilo = y >> 1, ihi = ((y + 1) >> 1) > 255 ? 255 : ((y + 1) >> 1);
    int jlo = x >> 1, jhi = ((x + 1) >> 1) > 255 ? 255 : ((x + 1) >> 1);
    for (int i = ilo; i <= ihi; ++i)
        for (int j = jlo; j <= jhi; ++j)
            atomicAdd(&L[i*256 + j], c);
}

// ---- generic pyramid downsample level l-1 -> l ----
__global__ void k_lvl(const float* __restrict__ in, float* __restrict__ out,
                      int sin, int sout) {
    int t = blockIdx.x * blockDim.x + threadIdx.x;
    int ss = sout * sout;
    if (t >= IMGS * ss) return;
    int img = t / ss;
    int r = t - img * ss;
    int i = r / sout;
    int j = r - i * sout;
    const float* m = in + (size_t)img * sin * sin;
    float s = 0.0f;
    for (int dy = -1; dy <= 1; ++dy) {
        int y = 2*i + dy;
        for (int dx = -1; dx <= 1; ++dx) {
            int x = 2*j + dx;
            s += (y >= 0 && y < sin && x >= 0 && x < sin) ? m[y*sin + x] : OOBV;
        }
    }
    out[t] = s / 9.0f;
}

// ---- ga = (grad0 + sum of upsampled levels)/10, one block per image-row ----
// vertical lerp of all 9 levels into LDS (520 floats incl. +1 pad per level),
// then 9 horizontal lerps per pixel.
__global__ __launch_bounds__(256) void k_ga(const float* __restrict__ mt,
                                            const float* __restrict__ pyr,
                                            float* __restrict__ ga) {
    __shared__ float vrow[520];
    int img = blockIdx.x >> 9;
    int h = blockIdx.x & 511;
    float hf = (float)h;

    // phase 1: vertically interpolated rows of levels 1..9 (+dup pad slot each)
    for (int e = threadIdx.x; e < 520; e += 256) {
        int l = 0, rem = e;
        while (true) {
            int len = (256 >> l) + 1;
            if (rem < len) break;
            rem -= len; ++l;
        }
        int s = 256 >> l;
        int x = rem < s ? rem : s - 1;          // pad slot duplicates last col
        float scale = (float)s * (1.0f / 512.0f);
        float fy = (hf + 0.5f) * scale - 0.5f;
        fy = fminf(fmaxf(fy, 0.0f), (float)(s - 1));   // edge clamp => exact weight-1
        float fyf = floorf(fy);
        int y0 = (int)fyf;
        float ty = fy - fyf;
        int yb = (y0 + 1 < s) ? y0 + 1 : s - 1;
        const float* Lp = pyr + (8388608 - (8388608 >> (2*l))) + (size_t)img * s * s;
        float a = Lp[y0*s + x], b = Lp[yb*s + x];
        vrow[e] = (1.0f - ty) * a + ty * b;
    }
    __syncthreads();

    // phase 2: two pixels per thread
    #pragma unroll
    for (int rep = 0; rep < 2; ++rep) {
        int w = threadIdx.x + rep * 256;
        int idx = img * HW + h * 512 + w;
        float wf = (float)w;
        float acc = -mt[idx];                   // grad0 (0.01*mo corrected later)
        #pragma unroll
        for (int l = 0; l < 9; ++l) {
            const int s = 256 >> l;
            const float scale = (float)s * (1.0f / 512.0f);
            float fx = (wf + 0.5f) * scale - 0.5f;
            fx = fminf(fmaxf(fx, 0.0f), (float)(s - 1));
            float fxf = floorf(fx);
            int x0 = (int)fxf;
            float tx = fx - fxf;
            const int vo = 512 - (512 >> l) + l;
            float a = vrow[vo + x0], b = vrow[vo + x0 + 1];
            acc += (1.0f - tx) * a + tx * b;
        }
        ga[idx] = acc / 10.0f;
    }
}

// ---- ga correction: +0.01/10 at set pixels (dedup'd, so plain RMW is safe) ----
__global__ void k_corrga(const int* __restrict__ cnt, const int* __restrict__ plist,
                         float* __restrict__ ga) {
    int k = blockIdx.x * blockDim.x + threadIdx.x;
    if (k >= *cnt) return;
    ga[plist[k]] += 0.001f;
}

// ---- optimizer state init + plmax[0] ----
__global__ void k_init(const float* __restrict__ pts, const float* __restrict__ mt,
                       float* __restrict__ p, float* __restrict__ sq,
                       float* __restrict__ plmax) {
    int i = blockIdx.x * blockDim.x + threadIdx.x;
    if (i >= NPTS) return;
    float px = pts[2*i], py = pts[2*i+1];
    p[2*i] = px; p[2*i+1] = py;
    sq[2*i] = 0.0f; sq[2*i+1] = 0.0f;
    int xi = clampi((int)rintf(px), 0, 511);
    int yi = clampi((int)rintf(py), 0, 511);
    int img = i >> 7, n = i & 127;
    float d = expf(-(float)n * 0.078125f);      // exp(-n/128*10), exact args
    float pl = (1.0f - mt[(size_t)img * HW + yi*512 + xi]) * d;
    atomicMax((int*)plmax, __float_as_int(pl)); // pl>0 => int-bit order == float order
}

// ---- one RMSprop step; carries plmax[t] -> plmax[t+1] ----
__global__ void k_step(const float* __restrict__ mt, const float* __restrict__ ga,
                       float* __restrict__ p, float* __restrict__ sq,
                       float* __restrict__ plmax, int t) {
    int i = blockIdx.x * blockDim.x + threadIdx.x;
    if (i >= NPTS) return;
    float plm = plmax[t];
    if (!(plm > 0.1f)) {                        // inactive: p frozen, propagate max
        if (i == 0) plmax[t+1] = plm;
        return;
    }
    float px = p[2*i], py = p[2*i+1];
    int xi = clampi((int)rintf(px), 0, 511);
    int yi = clampi((int)rintf(py), 0, 511);
    int img = i >> 7, n = i & 127;
    const float* M = mt + (size_t)img * HW;
    const float* G = ga + (size_t)img * HW;
    float d = expf(-(float)n * 0.078125f);
    float pl = (1.0f - M[yi*512 + xi]) * d;
    float gxp = (G[clampi(yi-1,0,511)*512 + xi] - G[clampi(yi+1,0,511)*512 + xi]) * 0.5f;
    float gyp = (G[yi*512 + clampi(xi-1,0,511)] - G[yi*512 + clampi(xi+1,0,511)]) * 0.5f;
    float g0 = -gyp * pl;                       // x component
    float g1 = -gxp * pl;                       // y component
    float s0 = 0.99f * sq[2*i]   + 0.01f * g0 * g0;
    float s1 = 0.99f * sq[2*i+1] + 0.01f * g1 * g1;
    float p0 = px - 0.2f * g0 / (sqrtf(s0) + 1e-8f);
    float p1 = py - 0.2f * g1 / (sqrtf(s1) + 1e-8f);
    p[2*i] = p0; p[2*i+1] = p1;
    sq[2*i] = s0; sq[2*i+1] = s1;
    int xi2 = clampi((int)rintf(p0), 0, 511);
    int yi2 = clampi((int)rintf(p1), 0, 511);
    float pl2 = (1.0f - M[yi2*512 + xi2]) * d;
    atomicMax((int*)(plmax + t + 1), __float_as_int(pl2));
}

// ---- final: masks_opt scatter + p_opt write ----
__global__ void k_final(const float* __restrict__ p, float* __restrict__ mopt,
                        float* __restrict__ pout) {
    int i = blockIdx.x * blockDim.x + threadIdx.x;
    if (i >= NPTS) return;
    float px = p[2*i], py = p[2*i+1];
    pout[2*i] = px; pout[2*i+1] = py;
    int xi = clampi((int)rintf(px), 0, 511);
    int yi = clampi((int)rintf(py), 0, 511);
    mopt[(i >> 7) * HW + yi*512 + xi] = 1.0f;
}

extern "C" void kernel_launch(void* const* d_in, const int* in_sizes, int n_in,
                              void* d_out, int out_size, void* d_ws, size_t ws_size,
                              hipStream_t stream) {
    const float* pts = (const float*)d_in[0];
    const float* mt  = (const float*)d_in[1];
    if (in_sizes[0] != NPTS * 2) { const float* tmp = pts; pts = mt; mt = tmp; }

    float* out  = (float*)d_out;
    float* mo   = out;                          // masks_out
    float* ga   = out + (size_t)IMGS * HW;      // masks_opt region = ga scratch
    float* pout = out + 2 * (size_t)IMGS * HW;  // p_opt

    float* ws    = (float*)d_ws;
    float* pyr   = ws + PYR_OFF;
    float* p     = ws + P_OFF;
    float* sq    = ws + SQ_OFF;
    float* plmax = ws + PLMAX_OFF;
    int*   cnt   = (int*)(ws + CNT_OFF);
    int*   plist = (int*)(ws + LIST_OFF);

    hipMemsetAsync(mo, 0, (size_t)IMGS * HW * sizeof(float), stream);
    hipMemsetAsync(plmax, 0, 12 * sizeof(float), stream);   // plmax[0..10] + cnt

    k_scatter<<<NPTS/256, 256, 0, stream>>>(pts, mo, cnt, plist);
    k_lvl1<<<IMGS*65536/256, 256, 0, stream>>>(mt, pyr);
    k_corr1<<<NPTS/256, 256, 0, stream>>>(cnt, plist, pyr);

    int offs[10];
    offs[1] = 0;
    for (int l = 2; l <= 9; ++l) {
        int sprev = 512 >> (l - 1);
        offs[l] = offs[l-1] + IMGS * sprev * sprev;
    }
    for (int l = 2; l <= 9; ++l) {
        int sin = 512 >> (l - 1), sout = 512 >> l;
        int tot = IMGS * sout * sout;
        k_lvl<<<(tot + 255)/256, 256, 0, stream>>>(pyr + offs[l-1], pyr + offs[l], sin, sout);
    }

    k_ga<<<IMGS*512, 256, 0, stream>>>(mt, pyr, ga);
    k_corrga<<<NPTS/256, 256, 0, stream>>>(cnt, plist, ga);
    k_init<<<NPTS/256, 256, 0, stream>>>(pts, mt, p, sq, plmax);
    for (int t = 0; t < 10; ++t)
        k_step<<<NPTS/256, 256, 0, stream>>>(mt, ga, p, sq, plmax, t);

    hipMemsetAsync(ga, 0, (size_t)IMGS * HW * sizeof(float), stream);
    k_final<<<NPTS/256, 256, 0, stream>>>(p, ga, pout);
}